// Round 5
// baseline (183.531 us; speedup 1.0000x reference)
//
#include <hip/hip_runtime.h>

#define N_USERS 200000
#define N_ITEMS 100000
#define N_NODES 300000
#define N_EDGES 4800000
#define EMB 64
#define BATCH 4096
#define NSLOTS (2 * BATCH)
#define CAP 64   // bucket capacity; Poisson(16) overflow P ~ 1e-18

typedef unsigned int u32;

// K1: init node2slot (-1) + slot_count (0). Harness poisons ws with 0xAA each call.
__global__ void k_init(int* __restrict__ node2slot, u32* __restrict__ slot_count) {
    int i = blockIdx.x * blockDim.x + threadIdx.x;
    if (i < N_NODES) node2slot[i] = -1;
    if (i < NSLOTS) slot_count[i] = 0u;
}

// K2: canonical slot per selected node (CAS; duplicate ids share the winner)
__global__ void k_map(const int* __restrict__ user_id, const int* __restrict__ item_id,
                      int* __restrict__ node2slot) {
    int b = blockIdx.x * blockDim.x + threadIdx.x;
    if (b >= NSLOTS) return;
    int node = (b < BATCH) ? user_id[b] : (N_USERS + item_id[b - BATCH]);
    atomicCAS(&node2slot[node], -1, b);
}

// K3: stream adj_row as int4; membership = node2slot[r] >= 0 (1.2MB, L2-hot).
// Hit lanes load (col,val) at stream position and store packed 8B bucket entry.
__global__ void k_filter(const int4* __restrict__ adj_row4, const int* __restrict__ adj_col,
                         const float* __restrict__ vals, const int* __restrict__ node2slot,
                         u32* __restrict__ slot_count, uint2* __restrict__ bucket) {
    u32 i = blockIdx.x * blockDim.x + threadIdx.x;
    if (i >= N_EDGES / 4) return;
    int4 rr = adj_row4[i];
    u32 e0 = i * 4u;
    #pragma unroll
    for (int k = 0; k < 4; k++) {
        int s = node2slot[(&rr.x)[k]];
        if (s >= 0) {
            u32 e = e0 + (u32)k;
            u32 p = atomicAdd(&slot_count[s], 1u);   // 8192 addrs, L2-hot, low contention
            if (p < CAP) {
                uint2 ent;
                ent.x = (u32)adj_col[e];
                ent.y = __float_as_uint(vals[e]);
                bucket[(u32)s * CAP + p] = ent;      // 8B scatter
            }
        }
    }
}

// K4: one wave per output slot. Duplicates read the canonical slot's bucket (pure read,
// no ordering dep). Lanes j<cnt pre-gather entries, shfl-broadcast, coalesced 256B emb
// rows, register accumulate, write final 2*x0+acc to out. No atomics, no second pass.
__global__ void k_accum(const int* __restrict__ node2slot,
                        const u32* __restrict__ slot_count, const uint2* __restrict__ bucket,
                        const float* __restrict__ user_emb, const float* __restrict__ item_emb,
                        const int* __restrict__ user_id, const int* __restrict__ item_id,
                        float* __restrict__ out) {
    int lane = threadIdx.x & 63;
    u32 o = (u32)(blockIdx.x * blockDim.x + threadIdx.x) >> 6;
    if (o >= NSLOTS) return;
    int node = (o < BATCH) ? user_id[o] : (N_USERS + item_id[o - BATCH]);
    int s = node2slot[node];                 // canonical slot (== o except duplicates)
    u32 cnt = slot_count[s];
    if (cnt > CAP) cnt = CAP;
    int c = 0; float v = 0.f;
    if ((u32)lane < cnt) {
        uint2 ent = bucket[(u32)s * CAP + (u32)lane];   // coalesced 8B
        c = (int)ent.x;
        v = __uint_as_float(ent.y);
    }
    float a0 = 0.f, a1 = 0.f, a2 = 0.f, a3 = 0.f;
    u32 j = 0;
    for (; j + 4 <= cnt; j += 4) {           // 4-way unroll: independent 256B row loads
        int c0 = __shfl(c, (int)j);     float v0 = __shfl(v, (int)j);
        int c1 = __shfl(c, (int)j + 1); float v1 = __shfl(v, (int)j + 1);
        int c2 = __shfl(c, (int)j + 2); float v2 = __shfl(v, (int)j + 2);
        int c3 = __shfl(c, (int)j + 3); float v3 = __shfl(v, (int)j + 3);
        const float* p0 = (c0 < N_USERS) ? user_emb + (size_t)c0 * EMB : item_emb + (size_t)(c0 - N_USERS) * EMB;
        const float* p1 = (c1 < N_USERS) ? user_emb + (size_t)c1 * EMB : item_emb + (size_t)(c1 - N_USERS) * EMB;
        const float* p2 = (c2 < N_USERS) ? user_emb + (size_t)c2 * EMB : item_emb + (size_t)(c2 - N_USERS) * EMB;
        const float* p3 = (c3 < N_USERS) ? user_emb + (size_t)c3 * EMB : item_emb + (size_t)(c3 - N_USERS) * EMB;
        a0 += v0 * p0[lane];
        a1 += v1 * p1[lane];
        a2 += v2 * p2[lane];
        a3 += v3 * p3[lane];
    }
    for (; j < cnt; j++) {
        int c0 = __shfl(c, (int)j); float v0 = __shfl(v, (int)j);
        const float* p0 = (c0 < N_USERS) ? user_emb + (size_t)c0 * EMB : item_emb + (size_t)(c0 - N_USERS) * EMB;
        a0 += v0 * p0[lane];
    }
    const float* xr = (node < N_USERS) ? user_emb + (size_t)node * EMB
                                       : item_emb + (size_t)(node - N_USERS) * EMB;
    out[(size_t)o * EMB + lane] = 2.f * xr[lane] + ((a0 + a1) + (a2 + a3));
}

extern "C" void kernel_launch(void* const* d_in, const int* in_sizes, int n_in,
                              void* d_out, int out_size, void* d_ws, size_t ws_size,
                              hipStream_t stream) {
    const float* user_emb = (const float*)d_in[0];
    const float* item_emb = (const float*)d_in[1];
    const int* adj_row = (const int*)d_in[2];
    const int* adj_col = (const int*)d_in[3];
    const float* adj_vals = (const float*)d_in[4];
    const int* user_id = (const int*)d_in[5];
    const int* item_id = (const int*)d_in[6];
    float* out = (float*)d_out;

    // ws layout (256B aligned): node2slot 1.2MB | slot_count 32KB | bucket 4MB
    char* ws = (char*)d_ws;
    size_t off = 0;
    int* node2slot  = (int*)(ws + off);  off += ((size_t)N_NODES * 4 + 255) & ~(size_t)255;
    u32* slot_count = (u32*)(ws + off);  off += ((size_t)NSLOTS * 4 + 255) & ~(size_t)255;
    uint2* bucket   = (uint2*)(ws + off);

    const int B = 256;
    k_init<<<(N_NODES + B - 1) / B, B, 0, stream>>>(node2slot, slot_count);
    k_map<<<(NSLOTS + B - 1) / B, B, 0, stream>>>(user_id, item_id, node2slot);
    k_filter<<<(N_EDGES / 4 + B - 1) / B, B, 0, stream>>>((const int4*)adj_row, adj_col,
                                                          adj_vals, node2slot,
                                                          slot_count, bucket);
    k_accum<<<(NSLOTS * 64 + B - 1) / B, B, 0, stream>>>(node2slot, slot_count, bucket,
                                                         user_emb, item_emb,
                                                         user_id, item_id, out);
}

// Round 6
// 177.061 us; speedup vs baseline: 1.0365x; 1.0365x over previous
//
#include <hip/hip_runtime.h>

#define N_USERS 200000
#define N_ITEMS 100000
#define N_NODES 300000
#define N_EDGES 4800000
#define EMB 64
#define BATCH 4096
#define NSLOTS (2 * BATCH)
#define NBITMAP ((N_NODES + 31) / 32)   // 9375 u32 = 37.5 KB -> L1-resident
#define CAP 64   // bucket capacity; Poisson(16) overflow P ~ 1e-18

typedef unsigned int u32;

// K1: init node2slot (-1), bitmap (0), slot_count (0). Harness poisons ws with 0xAA.
__global__ void k_init(int* __restrict__ node2slot, u32* __restrict__ bitmap,
                       u32* __restrict__ slot_count) {
    int i = blockIdx.x * blockDim.x + threadIdx.x;
    if (i < N_NODES) node2slot[i] = -1;
    if (i < NBITMAP) bitmap[i] = 0u;
    if (i < NSLOTS) slot_count[i] = 0u;
}

// K2: canonical slot per selected node (CAS; duplicate ids share winner) + membership bit
__global__ void k_map(const int* __restrict__ user_id, const int* __restrict__ item_id,
                      int* __restrict__ node2slot, u32* __restrict__ bitmap) {
    int b = blockIdx.x * blockDim.x + threadIdx.x;
    if (b >= NSLOTS) return;
    int node = (b < BATCH) ? user_id[b] : (N_USERS + item_id[b - BATCH]);
    atomicCAS(&node2slot[node], -1, b);
    atomicOr(&bitmap[node >> 5], 1u << (node & 31));
}

// K3: stream adj_row as int4; first-level membership via L1-hot 37.5KB bitmap
// (node2slot 1.2MB is only probed on actual hits, ~131k times not 4.8M).
// Hit lanes load (col,val) at stream position, store packed 8B bucket entry.
__global__ void k_filter(const int4* __restrict__ adj_row4, const int* __restrict__ adj_col,
                         const float* __restrict__ vals,
                         const u32* __restrict__ bitmap, const int* __restrict__ node2slot,
                         u32* __restrict__ slot_count, uint2* __restrict__ bucket) {
    u32 i = blockIdx.x * blockDim.x + threadIdx.x;
    if (i >= N_EDGES / 4) return;
    int4 rr = adj_row4[i];
    u32 e0 = i * 4u;
    // issue all 4 L1 probes up front (independent -> in flight together)
    u32 w0 = bitmap[rr.x >> 5];
    u32 w1 = bitmap[rr.y >> 5];
    u32 w2 = bitmap[rr.z >> 5];
    u32 w3 = bitmap[rr.w >> 5];
    bool h0 = (w0 >> (rr.x & 31)) & 1u;
    bool h1 = (w1 >> (rr.y & 31)) & 1u;
    bool h2 = (w2 >> (rr.z & 31)) & 1u;
    bool h3 = (w3 >> (rr.w & 31)) & 1u;
    if (h0) { int s = node2slot[rr.x]; u32 p = atomicAdd(&slot_count[s], 1u);
        if (p < CAP) { uint2 t; t.x = (u32)adj_col[e0];     t.y = __float_as_uint(vals[e0]);     bucket[(u32)s * CAP + p] = t; } }
    if (h1) { int s = node2slot[rr.y]; u32 p = atomicAdd(&slot_count[s], 1u);
        if (p < CAP) { uint2 t; t.x = (u32)adj_col[e0 + 1]; t.y = __float_as_uint(vals[e0 + 1]); bucket[(u32)s * CAP + p] = t; } }
    if (h2) { int s = node2slot[rr.z]; u32 p = atomicAdd(&slot_count[s], 1u);
        if (p < CAP) { uint2 t; t.x = (u32)adj_col[e0 + 2]; t.y = __float_as_uint(vals[e0 + 2]); bucket[(u32)s * CAP + p] = t; } }
    if (h3) { int s = node2slot[rr.w]; u32 p = atomicAdd(&slot_count[s], 1u);
        if (p < CAP) { uint2 t; t.x = (u32)adj_col[e0 + 3]; t.y = __float_as_uint(vals[e0 + 3]); bucket[(u32)s * CAP + p] = t; } }
}

// K4: one wave per output slot. Duplicates read the canonical slot's bucket (pure read).
// Lanes j<cnt pre-gather entries, shfl-broadcast, coalesced 256B emb rows, register
// accumulate, write final 2*x0+acc to out. No atomics, no second pass.
__global__ void k_accum(const int* __restrict__ node2slot,
                        const u32* __restrict__ slot_count, const uint2* __restrict__ bucket,
                        const float* __restrict__ user_emb, const float* __restrict__ item_emb,
                        const int* __restrict__ user_id, const int* __restrict__ item_id,
                        float* __restrict__ out) {
    int lane = threadIdx.x & 63;
    u32 o = (u32)(blockIdx.x * blockDim.x + threadIdx.x) >> 6;
    if (o >= NSLOTS) return;
    int node = (o < BATCH) ? user_id[o] : (N_USERS + item_id[o - BATCH]);
    int s = node2slot[node];                 // canonical slot (== o except duplicates)
    u32 cnt = slot_count[s];
    if (cnt > CAP) cnt = CAP;
    int c = 0; float v = 0.f;
    if ((u32)lane < cnt) {
        uint2 ent = bucket[(u32)s * CAP + (u32)lane];   // coalesced 8B
        c = (int)ent.x;
        v = __uint_as_float(ent.y);
    }
    float a0 = 0.f, a1 = 0.f, a2 = 0.f, a3 = 0.f;
    u32 j = 0;
    for (; j + 4 <= cnt; j += 4) {           // 4-way unroll: independent 256B row loads
        int c0 = __shfl(c, (int)j);     float v0 = __shfl(v, (int)j);
        int c1 = __shfl(c, (int)j + 1); float v1 = __shfl(v, (int)j + 1);
        int c2 = __shfl(c, (int)j + 2); float v2 = __shfl(v, (int)j + 2);
        int c3 = __shfl(c, (int)j + 3); float v3 = __shfl(v, (int)j + 3);
        const float* p0 = (c0 < N_USERS) ? user_emb + (size_t)c0 * EMB : item_emb + (size_t)(c0 - N_USERS) * EMB;
        const float* p1 = (c1 < N_USERS) ? user_emb + (size_t)c1 * EMB : item_emb + (size_t)(c1 - N_USERS) * EMB;
        const float* p2 = (c2 < N_USERS) ? user_emb + (size_t)c2 * EMB : item_emb + (size_t)(c2 - N_USERS) * EMB;
        const float* p3 = (c3 < N_USERS) ? user_emb + (size_t)c3 * EMB : item_emb + (size_t)(c3 - N_USERS) * EMB;
        a0 += v0 * p0[lane];
        a1 += v1 * p1[lane];
        a2 += v2 * p2[lane];
        a3 += v3 * p3[lane];
    }
    for (; j < cnt; j++) {
        int c0 = __shfl(c, (int)j); float v0 = __shfl(v, (int)j);
        const float* p0 = (c0 < N_USERS) ? user_emb + (size_t)c0 * EMB : item_emb + (size_t)(c0 - N_USERS) * EMB;
        a0 += v0 * p0[lane];
    }
    const float* xr = (node < N_USERS) ? user_emb + (size_t)node * EMB
                                       : item_emb + (size_t)(node - N_USERS) * EMB;
    out[(size_t)o * EMB + lane] = 2.f * xr[lane] + ((a0 + a1) + (a2 + a3));
}

extern "C" void kernel_launch(void* const* d_in, const int* in_sizes, int n_in,
                              void* d_out, int out_size, void* d_ws, size_t ws_size,
                              hipStream_t stream) {
    const float* user_emb = (const float*)d_in[0];
    const float* item_emb = (const float*)d_in[1];
    const int* adj_row = (const int*)d_in[2];
    const int* adj_col = (const int*)d_in[3];
    const float* adj_vals = (const float*)d_in[4];
    const int* user_id = (const int*)d_in[5];
    const int* item_id = (const int*)d_in[6];
    float* out = (float*)d_out;

    // ws layout (256B aligned): node2slot 1.2MB | bitmap 37.5KB | slot_count 32KB | bucket 4MB
    char* ws = (char*)d_ws;
    size_t off = 0;
    int* node2slot  = (int*)(ws + off);  off += ((size_t)N_NODES * 4 + 255) & ~(size_t)255;
    u32* bitmap     = (u32*)(ws + off);  off += ((size_t)NBITMAP * 4 + 255) & ~(size_t)255;
    u32* slot_count = (u32*)(ws + off);  off += ((size_t)NSLOTS * 4 + 255) & ~(size_t)255;
    uint2* bucket   = (uint2*)(ws + off);

    const int B = 256;
    k_init<<<(N_NODES + B - 1) / B, B, 0, stream>>>(node2slot, bitmap, slot_count);
    k_map<<<(NSLOTS + B - 1) / B, B, 0, stream>>>(user_id, item_id, node2slot, bitmap);
    k_filter<<<(N_EDGES / 4 + B - 1) / B, B, 0, stream>>>((const int4*)adj_row, adj_col,
                                                          adj_vals, bitmap, node2slot,
                                                          slot_count, bucket);
    k_accum<<<(NSLOTS * 64 + B - 1) / B, B, 0, stream>>>(node2slot, slot_count, bucket,
                                                         user_emb, item_emb,
                                                         user_id, item_id, out);
}